// Round 1
// baseline (174.867 us; speedup 1.0000x reference)
//
#include <hip/hip_runtime.h>
#include <hip/hip_bf16.h>

#define NS 25
#define NQ 200
#define FG 16
#define FL 64
#define FTOT 80
#define D 512
#define WAY 5

typedef unsigned short u16;
typedef __attribute__((ext_vector_type(8))) short short8;
typedef __attribute__((ext_vector_type(4))) float floatx4;
typedef __attribute__((ext_vector_type(4))) int intx4;

__device__ inline u16 f2bf(float x) {
    union { float f; unsigned u; } v; v.f = x;
    unsigned r = v.u + 0x7fff + ((v.u >> 16) & 1);   // RNE
    return (u16)(r >> 16);
}

// One wave per 512-elem row: L2-normalize, cast to bf16, write concat layout.
__global__ void normalize_kernel(const float* __restrict__ sg, const float* __restrict__ sl,
                                 const float* __restrict__ qg, const float* __restrict__ ql,
                                 u16* __restrict__ Sn, u16* __restrict__ Qn) {
    int wave = (blockIdx.x * blockDim.x + threadIdx.x) >> 6;
    int lane = threadIdx.x & 63;
    const int totalRows = NS * FTOT + NQ * FTOT;   // 18000
    if (wave >= totalRows) return;

    const float* src;
    u16* dst;
    if (wave < NS * FTOT) {
        int s = wave / FTOT, f = wave % FTOT;
        src = (f < FG) ? sg + (size_t)(s * FG + f) * D
                       : sl + (size_t)(s * FL + (f - FG)) * D;
        dst = Sn + (size_t)wave * D;
    } else {
        int r = wave - NS * FTOT;
        int q = r / FTOT, f = r % FTOT;
        src = (f < FG) ? qg + (size_t)(q * FG + f) * D
                       : ql + (size_t)(q * FL + (f - FG)) * D;
        dst = Qn + (size_t)r * D;
    }

    float4 v0 = ((const float4*)src)[lane];
    float4 v1 = ((const float4*)src)[lane + 64];
    float ss = v0.x*v0.x + v0.y*v0.y + v0.z*v0.z + v0.w*v0.w
             + v1.x*v1.x + v1.y*v1.y + v1.z*v1.z + v1.w*v1.w;
    #pragma unroll
    for (int off = 32; off > 0; off >>= 1) ss += __shfl_xor(ss, off, 64);
    float scale = 1.0f / fmaxf(sqrtf(ss), 1e-12f);

    ushort4 o0, o1;
    o0.x = f2bf(v0.x * scale); o0.y = f2bf(v0.y * scale);
    o0.z = f2bf(v0.z * scale); o0.w = f2bf(v0.w * scale);
    o1.x = f2bf(v1.x * scale); o1.y = f2bf(v1.y * scale);
    o1.z = f2bf(v1.z * scale); o1.w = f2bf(v1.w * scale);
    ((ushort4*)dst)[lane]      = o0;
    ((ushort4*)dst)[lane + 64] = o1;
}

// One block per (s,q) pair. LDS-stage K-chunks of both 80x512 bf16 row blocks,
// 4 waves x 7 MFMA 16x16 tiles cover the 80x80 sim block; epilogue sums (1-sim)^2.
#define LDS_PITCH 136   // 128 + 8 bf16 pad (16B) to break bank-conflict stride
__global__ __launch_bounds__(256) void pair_kernel(const u16* __restrict__ Sn,
                                                   const u16* __restrict__ Qn,
                                                   float* __restrict__ cum) {
    __shared__ u16 As[FTOT][LDS_PITCH];
    __shared__ u16 Bs[FTOT][LDS_PITCH];
    __shared__ float red[4];

    const int q = blockIdx.x;
    const int s = blockIdx.y;
    const int tid = threadIdx.x;
    const int lane = tid & 63;
    const int w = tid >> 6;
    const int lm = lane & 15;
    const int lq = lane >> 4;

    floatx4 acc[7];
    int arow[7], brow[7];
    #pragma unroll
    for (int tt = 0; tt < 7; ++tt) {
        acc[tt] = (floatx4){0.f, 0.f, 0.f, 0.f};
        int t = tt * 4 + w; if (t > 24) t = 24;     // clamp; masked in epilogue
        int i = t / 5, j = t % 5;
        arow[tt] = (i * 16 + lm) * LDS_PITCH + lq * 8;
        brow[tt] = (j * 16 + lm) * LDS_PITCH + lq * 8;
    }

    const u16* Sbase = Sn + (size_t)s * FTOT * D;
    const u16* Qbase = Qn + (size_t)q * FTOT * D;

    for (int kc = 0; kc < 4; ++kc) {
        __syncthreads();   // protect LDS from previous chunk's readers
        #pragma unroll
        for (int it = 0; it < 5; ++it) {
            int idx = tid + it * 256;          // 0..1279
            int row = idx >> 4, c16 = idx & 15;
            *(intx4*)&As[row][c16 * 8] = *(const intx4*)(Sbase + row * D + kc * 128 + c16 * 8);
            *(intx4*)&Bs[row][c16 * 8] = *(const intx4*)(Qbase + row * D + kc * 128 + c16 * 8);
        }
        __syncthreads();
        #pragma unroll
        for (int kk = 0; kk < 4; ++kk) {
            #pragma unroll
            for (int tt = 0; tt < 7; ++tt) {
                short8 a = *(const short8*)((const u16*)As + arow[tt] + kk * 32);
                short8 b = *(const short8*)((const u16*)Bs + brow[tt] + kk * 32);
                acc[tt] = __builtin_amdgcn_mfma_f32_16x16x32_bf16(a, b, acc[tt], 0, 0, 0);
            }
        }
    }

    float local = 0.f;
    #pragma unroll
    for (int tt = 0; tt < 7; ++tt) {
        if (tt * 4 + w < 25) {
            #pragma unroll
            for (int r = 0; r < 4; ++r) {
                float d = 1.0f - acc[tt][r];
                local += d * d;
            }
        }
    }
    #pragma unroll
    for (int off = 32; off > 0; off >>= 1) local += __shfl_down(local, off, 64);
    if (lane == 0) red[w] = local;
    __syncthreads();
    if (tid == 0) cum[s * NQ + q] = 2.0f * (red[0] + red[1] + red[2] + red[3]);
}

// logits[q,c] = -mean over class members of cum[s,q]
__global__ void logits_kernel(const float* __restrict__ cum, const int* __restrict__ labels,
                              float* __restrict__ out) {
    int g = blockIdx.x * blockDim.x + threadIdx.x;
    if (g >= NQ * WAY) return;
    int q = g / WAY, c = g % WAY;
    float sum = 0.f; int cnt = 0;
    for (int s = 0; s < NS; ++s) {
        if (labels[s] == c) { sum += cum[s * NQ + q]; cnt++; }
    }
    out[g] = -sum / (float)cnt;
}

extern "C" void kernel_launch(void* const* d_in, const int* in_sizes, int n_in,
                              void* d_out, int out_size, void* d_ws, size_t ws_size,
                              hipStream_t stream) {
    const float* sg = (const float*)d_in[0];
    const float* sl = (const float*)d_in[1];
    const int* labels = (const int*)d_in[2];
    const float* qg = (const float*)d_in[3];
    const float* ql = (const float*)d_in[4];
    float* out = (float*)d_out;

    u16* Sn = (u16*)d_ws;                       // 25*80*512 bf16 = 2,048,000 B
    u16* Qn = Sn + (size_t)NS * FTOT * D;       // 200*80*512 bf16 = 16,384,000 B
    float* cum = (float*)(Qn + (size_t)NQ * FTOT * D);  // 25*200 f32 = 20,000 B

    normalize_kernel<<<4500, 256, 0, stream>>>(sg, sl, qg, ql, Sn, Qn);
    dim3 g2(NQ, NS);
    pair_kernel<<<g2, 256, 0, stream>>>(Sn, Qn, cum);
    logits_kernel<<<(NQ * WAY + 255) / 256, 256, 0, stream>>>(cum, labels, out);
}

// Round 2
// 157.617 us; speedup vs baseline: 1.1094x; 1.1094x over previous
//
#include <hip/hip_runtime.h>

#define NS 25
#define NQ 200
#define FG 16
#define FL 64
#define FTOT 80
#define D 512
#define WAY 5
#define MROWS 2000    // 25*80 support rows
#define MPAD 2048     // padded to 16 blocks of 128
#define NROWS 16000   // 200*80 query rows

typedef unsigned short u16;
typedef __attribute__((ext_vector_type(8))) short short8;
typedef __attribute__((ext_vector_type(4))) float floatx4;
typedef __attribute__((ext_vector_type(4))) int intx4;

__device__ inline u16 f2bf(float x) {
    union { float f; unsigned u; } v; v.f = x;
    unsigned r = v.u + 0x7fff + ((v.u >> 16) & 1);   // RNE
    return (u16)(r >> 16);
}

__device__ inline void gload_lds16(const void* g, void* l) {
    __builtin_amdgcn_global_load_lds(
        (const __attribute__((address_space(1))) unsigned int*)g,
        (__attribute__((address_space(3))) unsigned int*)l, 16, 0, 0);
}

// One wave per 512-elem row: L2-normalize, cast bf16, write concat layout.
// Block 4500 instead zeroes cum[] and the Sn pad rows.
__global__ void normalize_kernel(const float* __restrict__ sg, const float* __restrict__ sl,
                                 const float* __restrict__ qg, const float* __restrict__ ql,
                                 u16* __restrict__ Sn, u16* __restrict__ Qn,
                                 float* __restrict__ cum) {
    if (blockIdx.x == 4500) {
        int tid = threadIdx.x;
        for (int i = tid; i < NS * NQ; i += 256) cum[i] = 0.f;
        intx4 z = {0, 0, 0, 0};
        intx4* pad = (intx4*)(Sn + (size_t)MROWS * D);   // 48 rows * 512 u16 = 3072 intx4
        for (int i = tid; i < (MPAD - MROWS) * D / 8; i += 256) pad[i] = z;
        return;
    }
    int wave = (blockIdx.x * blockDim.x + threadIdx.x) >> 6;
    int lane = threadIdx.x & 63;
    const int totalRows = MROWS + NROWS;   // 18000
    if (wave >= totalRows) return;

    const float* src;
    u16* dst;
    if (wave < MROWS) {
        int s = wave / FTOT, f = wave % FTOT;
        src = (f < FG) ? sg + (size_t)(s * FG + f) * D
                       : sl + (size_t)(s * FL + (f - FG)) * D;
        dst = Sn + (size_t)wave * D;
    } else {
        int r = wave - MROWS;
        int q = r / FTOT, f = r % FTOT;
        src = (f < FG) ? qg + (size_t)(q * FG + f) * D
                       : ql + (size_t)(q * FL + (f - FG)) * D;
        dst = Qn + (size_t)r * D;
    }

    float4 v0 = ((const float4*)src)[lane];
    float4 v1 = ((const float4*)src)[lane + 64];
    float ss = v0.x*v0.x + v0.y*v0.y + v0.z*v0.z + v0.w*v0.w
             + v1.x*v1.x + v1.y*v1.y + v1.z*v1.z + v1.w*v1.w;
    #pragma unroll
    for (int off = 32; off > 0; off >>= 1) ss += __shfl_xor(ss, off, 64);
    float scale = 1.0f / fmaxf(sqrtf(ss), 1e-12f);

    ushort4 o0, o1;
    o0.x = f2bf(v0.x * scale); o0.y = f2bf(v0.y * scale);
    o0.z = f2bf(v0.z * scale); o0.w = f2bf(v0.w * scale);
    o1.x = f2bf(v1.x * scale); o1.y = f2bf(v1.y * scale);
    o1.z = f2bf(v1.z * scale); o1.w = f2bf(v1.w * scale);
    ((ushort4*)dst)[lane]      = o0;
    ((ushort4*)dst)[lane + 64] = o1;
}

// m97-style NT GEMM: C = Sn * Qn^T over 128x128 tiles, BK=64, fused
// (1-sim)^2 epilogue reduced into cum[s][q] via per-wave shuffle + atomics.
__global__ __launch_bounds__(256) void gemm_kernel(const u16* __restrict__ Sn,
                                                   const u16* __restrict__ Qn,
                                                   float* __restrict__ cum) {
    __shared__ u16 As[128][64];   // unpadded: global_load_lds needs contiguous lane order
    __shared__ u16 Bs[128][64];

    const int bx = blockIdx.x;          // 0..124 (query cols)
    const int by = blockIdx.y;          // 0..15  (support rows)
    const int tid = threadIdx.x;
    const int lane = tid & 63;
    const int w = tid >> 6;
    const int lm = lane & 15;
    const int lq = lane >> 4;
    const int mw0 = (w >> 1) * 64;      // wave row offset in tile
    const int nw0 = (w & 1) * 64;       // wave col offset in tile

    floatx4 acc[4][4];
    #pragma unroll
    for (int i = 0; i < 4; ++i)
        #pragma unroll
        for (int j = 0; j < 4; ++j) acc[i][j] = (floatx4){0.f, 0.f, 0.f, 0.f};

    const u16* Sbase = Sn + (size_t)by * 128 * D;
    const u16* Qbase = Qn + (size_t)bx * 128 * D;
    const int grow = lane >> 3;         // 0..7 rows within 8-row slab
    const int gcol = (lane & 7) * 8;    // u16 offset within 64-wide k slice

    for (int kc = 0; kc < 8; ++kc) {
        const int k0 = kc * 64;
        __syncthreads();                // prev chunk's readers done
        #pragma unroll
        for (int t = 0; t < 4; ++t) {
            const int ii = w * 4 + t;   // slab 0..15, 8 rows each
            gload_lds16(Sbase + (size_t)(ii * 8 + grow) * D + k0 + gcol,
                        (u16*)As + ii * 512);
            gload_lds16(Qbase + (size_t)(ii * 8 + grow) * D + k0 + gcol,
                        (u16*)Bs + ii * 512);
        }
        __syncthreads();                // drains vmcnt (global_load_lds) too
        #pragma unroll
        for (int ks = 0; ks < 2; ++ks) {
            short8 a[4], b[4];
            #pragma unroll
            for (int i = 0; i < 4; ++i) {
                a[i] = *(const short8*)&As[mw0 + i * 16 + lm][ks * 32 + lq * 8];
                b[i] = *(const short8*)&Bs[nw0 + i * 16 + lm][ks * 32 + lq * 8];
            }
            #pragma unroll
            for (int i = 0; i < 4; ++i)
                #pragma unroll
                for (int j = 0; j < 4; ++j)
                    acc[i][j] = __builtin_amdgcn_mfma_f32_16x16x32_bf16(a[i], b[j], acc[i][j], 0, 0, 0);
        }
    }

    // Epilogue: (1-sim)^2, reduce into <=2x2 (s,q) group cells per wave.
    const int rbase = by * 128 + mw0;
    const int cbase = bx * 128 + nw0;
    const int sLo = rbase / FTOT;
    const int qLo = cbase / FTOT;
    float l00 = 0.f, l01 = 0.f, l10 = 0.f, l11 = 0.f;
    #pragma unroll
    for (int i = 0; i < 4; ++i) {
        #pragma unroll
        for (int r = 0; r < 4; ++r) {
            const int gm = rbase + i * 16 + lq * 4 + r;   // C/D: row=(lane>>4)*4+reg
            if (gm < MROWS) {
                const bool s0 = (gm / FTOT == sLo);
                #pragma unroll
                for (int j = 0; j < 4; ++j) {
                    const int gn = cbase + j * 16 + lm;    // C/D: col=lane&15
                    const bool q0 = (gn / FTOT == qLo);
                    const float d = 1.0f - acc[i][j][r];
                    const float v = d * d;
                    l00 += (s0 && q0)   ? v : 0.f;
                    l01 += (s0 && !q0)  ? v : 0.f;
                    l10 += (!s0 && q0)  ? v : 0.f;
                    l11 += (!s0 && !q0) ? v : 0.f;
                }
            }
        }
    }
    #pragma unroll
    for (int off = 32; off > 0; off >>= 1) {
        l00 += __shfl_down(l00, off, 64);
        l01 += __shfl_down(l01, off, 64);
        l10 += __shfl_down(l10, off, 64);
        l11 += __shfl_down(l11, off, 64);
    }
    if (lane == 0) {
        if (l00 != 0.f) atomicAdd(&cum[sLo * NQ + qLo], l00);
        if (l01 != 0.f) atomicAdd(&cum[sLo * NQ + qLo + 1], l01);
        if (l10 != 0.f) atomicAdd(&cum[(sLo + 1) * NQ + qLo], l10);
        if (l11 != 0.f) atomicAdd(&cum[(sLo + 1) * NQ + qLo + 1], l11);
    }
}

// logits[q,c] = -2 * mean over class members of cum[s,q]  (cum holds fro2)
__global__ void logits_kernel(const float* __restrict__ cum, const int* __restrict__ labels,
                              float* __restrict__ out) {
    int g = blockIdx.x * blockDim.x + threadIdx.x;
    if (g >= NQ * WAY) return;
    int q = g / WAY, c = g % WAY;
    float sum = 0.f; int cnt = 0;
    for (int s = 0; s < NS; ++s) {
        if (labels[s] == c) { sum += cum[s * NQ + q]; cnt++; }
    }
    out[g] = -2.0f * sum / (float)cnt;
}

extern "C" void kernel_launch(void* const* d_in, const int* in_sizes, int n_in,
                              void* d_out, int out_size, void* d_ws, size_t ws_size,
                              hipStream_t stream) {
    const float* sg = (const float*)d_in[0];
    const float* sl = (const float*)d_in[1];
    const int* labels = (const int*)d_in[2];
    const float* qg = (const float*)d_in[3];
    const float* ql = (const float*)d_in[4];
    float* out = (float*)d_out;

    u16* Sn = (u16*)d_ws;                        // 2048*512 bf16 = 2 MB (padded)
    u16* Qn = Sn + (size_t)MPAD * D;             // 16000*512 bf16 = 16.4 MB
    float* cum = (float*)(Qn + (size_t)NROWS * D);  // 25*200 f32

    normalize_kernel<<<4501, 256, 0, stream>>>(sg, sl, qg, ql, Sn, Qn, cum);
    dim3 g2(125, 16);
    gemm_kernel<<<g2, 256, 0, stream>>>(Sn, Qn, cum);
    logits_kernel<<<(NQ * WAY + 255) / 256, 256, 0, stream>>>(cum, labels, out);
}

// Round 3
// 153.834 us; speedup vs baseline: 1.1367x; 1.0246x over previous
//
#include <hip/hip_runtime.h>

#define NS 25
#define NQ 200
#define FG 16
#define FL 64
#define FTOT 80
#define D 512
#define WAY 5
#define MROWS 2000    // 25*80 support rows
#define MPAD 2080     // padded to 13 tiles of 160
#define NROWS 16000   // 200*80 query rows

typedef unsigned short u16;
typedef __attribute__((ext_vector_type(8))) short short8;
typedef __attribute__((ext_vector_type(4))) float floatx4;
typedef __attribute__((ext_vector_type(4))) int intx4;

__device__ inline u16 f2bf(float x) {
    union { float f; unsigned u; } v; v.f = x;
    unsigned r = v.u + 0x7fff + ((v.u >> 16) & 1);   // RNE
    return (u16)(r >> 16);
}

__device__ inline void gload_lds16(const void* g, void* l) {
    __builtin_amdgcn_global_load_lds(
        (const __attribute__((address_space(1))) unsigned int*)g,
        (__attribute__((address_space(3))) unsigned int*)l, 16, 0, 0);
}

// One wave per 512-elem row: L2-normalize, cast bf16, write concat layout.
// Block 4500 zeroes the Sn pad rows (2000..2079).
__global__ void normalize_kernel(const float* __restrict__ sg, const float* __restrict__ sl,
                                 const float* __restrict__ qg, const float* __restrict__ ql,
                                 u16* __restrict__ Sn, u16* __restrict__ Qn) {
    if (blockIdx.x == 4500) {
        intx4 z = {0, 0, 0, 0};
        intx4* pad = (intx4*)(Sn + (size_t)MROWS * D);   // 80 rows * 512 u16 = 5120 intx4
        for (int i = threadIdx.x; i < (MPAD - MROWS) * D / 8; i += 256) pad[i] = z;
        return;
    }
    int wave = (blockIdx.x * blockDim.x + threadIdx.x) >> 6;
    int lane = threadIdx.x & 63;
    const int totalRows = MROWS + NROWS;   // 18000
    if (wave >= totalRows) return;

    const float* src;
    u16* dst;
    if (wave < MROWS) {
        int s = wave / FTOT, f = wave % FTOT;
        src = (f < FG) ? sg + (size_t)(s * FG + f) * D
                       : sl + (size_t)(s * FL + (f - FG)) * D;
        dst = Sn + (size_t)wave * D;
    } else {
        int r = wave - MROWS;
        int q = r / FTOT, f = r % FTOT;
        src = (f < FG) ? qg + (size_t)(q * FG + f) * D
                       : ql + (size_t)(q * FL + (f - FG)) * D;
        dst = Qn + (size_t)r * D;
    }

    float4 v0 = ((const float4*)src)[lane];
    float4 v1 = ((const float4*)src)[lane + 64];
    float ss = v0.x*v0.x + v0.y*v0.y + v0.z*v0.z + v0.w*v0.w
             + v1.x*v1.x + v1.y*v1.y + v1.z*v1.z + v1.w*v1.w;
    #pragma unroll
    for (int off = 32; off > 0; off >>= 1) ss += __shfl_xor(ss, off, 64);
    float scale = 1.0f / fmaxf(sqrtf(ss), 1e-12f);

    ushort4 o0, o1;
    o0.x = f2bf(v0.x * scale); o0.y = f2bf(v0.y * scale);
    o0.z = f2bf(v0.z * scale); o0.w = f2bf(v0.w * scale);
    o1.x = f2bf(v1.x * scale); o1.y = f2bf(v1.y * scale);
    o1.z = f2bf(v1.z * scale); o1.w = f2bf(v1.w * scale);
    ((ushort4*)dst)[lane]      = o0;
    ((ushort4*)dst)[lane + 64] = o1;
}

// 160x160-tile NT GEMM aligned to the 80-row group structure.
// 4 waves in 2x2; each wave owns one 80x80 (s,q) block = 5x5 MFMA 16x16x32 tiles.
// Epilogue: local = sum (1-sim)^2 over the wave's block -> one plain store.
__global__ __launch_bounds__(256, 3) void gemm_kernel(const u16* __restrict__ Sn,
                                                      const u16* __restrict__ Qn,
                                                      float* __restrict__ cum) {
    __shared__ u16 As[160][64];   // unpadded: global_load_lds needs contiguous lane order
    __shared__ u16 Bs[160][64];

    const int bx = blockIdx.x;          // 0..99  (query groups, 2 per block)
    const int by = blockIdx.y;          // 0..12  (support groups, 2 per block)
    const int tid = threadIdx.x;
    const int lane = tid & 63;
    const int w = tid >> 6;
    const int lm = lane & 15;
    const int lq = lane >> 4;
    const int wr = w >> 1;              // 0..1: which 80-row half
    const int wc = w & 1;               // 0..1: which 80-col half

    floatx4 acc[5][5];
    #pragma unroll
    for (int i = 0; i < 5; ++i)
        #pragma unroll
        for (int j = 0; j < 5; ++j) acc[i][j] = (floatx4){0.f, 0.f, 0.f, 0.f};

    const u16* Sbase = Sn + (size_t)by * 160 * D;
    const u16* Qbase = Qn + (size_t)bx * 160 * D;
    const int grow = lane >> 3;         // 0..7 rows within an 8-row slab
    const int gcol = (lane & 7) * 8;    // u16 offset within 64-wide k slice

    // waves 0,1 stage A (slabs 0..19), waves 2,3 stage B (slabs 0..19)
    const u16* gsrc = (w < 2) ? Sbase : Qbase;
    u16* ldst = (w < 2) ? (u16*)As : (u16*)Bs;
    const int slab0 = (w & 1) * 10;

    for (int kc = 0; kc < 8; ++kc) {
        const int k0 = kc * 64;
        __syncthreads();                // prev chunk's readers done
        #pragma unroll
        for (int t = 0; t < 10; ++t) {
            const int sl = slab0 + t;   // slab 0..19, 8 rows each
            gload_lds16(gsrc + (size_t)(sl * 8 + grow) * D + k0 + gcol,
                        ldst + sl * 512);
        }
        __syncthreads();                // drains vmcnt (global_load_lds) too
        #pragma unroll
        for (int ks = 0; ks < 2; ++ks) {
            short8 a[5], b[5];
            #pragma unroll
            for (int i = 0; i < 5; ++i)
                a[i] = *(const short8*)&As[wr * 80 + i * 16 + lm][ks * 32 + lq * 8];
            #pragma unroll
            for (int j = 0; j < 5; ++j)
                b[j] = *(const short8*)&Bs[wc * 80 + j * 16 + lm][ks * 32 + lq * 8];
            #pragma unroll
            for (int i = 0; i < 5; ++i)
                #pragma unroll
                for (int j = 0; j < 5; ++j)
                    acc[i][j] = __builtin_amdgcn_mfma_f32_16x16x32_bf16(a[i], b[j], acc[i][j], 0, 0, 0);
        }
    }

    // Epilogue: sum (1-sim)^2 over the wave's whole 80x80 block.
    float local = 0.f;
    #pragma unroll
    for (int i = 0; i < 5; ++i)
        #pragma unroll
        for (int j = 0; j < 5; ++j)
            #pragma unroll
            for (int r = 0; r < 4; ++r) {
                const float d = 1.0f - acc[i][j][r];
                local = fmaf(d, d, local);
            }
    #pragma unroll
    for (int off = 32; off > 0; off >>= 1) local += __shfl_down(local, off, 64);

    const int sIdx = by * 2 + wr;       // 0..25 (25 = pad group, dropped)
    const int qIdx = bx * 2 + wc;       // 0..199
    if (lane == 0 && sIdx < NS) cum[sIdx * NQ + qIdx] = local;
}

// logits[q,c] = -2 * mean over class members of cum[s,q]  (cum holds fro2)
__global__ void logits_kernel(const float* __restrict__ cum, const int* __restrict__ labels,
                              float* __restrict__ out) {
    int g = blockIdx.x * blockDim.x + threadIdx.x;
    if (g >= NQ * WAY) return;
    int q = g / WAY, c = g % WAY;
    float sum = 0.f; int cnt = 0;
    for (int s = 0; s < NS; ++s) {
        if (labels[s] == c) { sum += cum[s * NQ + q]; cnt++; }
    }
    out[g] = -2.0f * sum / (float)cnt;
}

extern "C" void kernel_launch(void* const* d_in, const int* in_sizes, int n_in,
                              void* d_out, int out_size, void* d_ws, size_t ws_size,
                              hipStream_t stream) {
    const float* sg = (const float*)d_in[0];
    const float* sl = (const float*)d_in[1];
    const int* labels = (const int*)d_in[2];
    const float* qg = (const float*)d_in[3];
    const float* ql = (const float*)d_in[4];
    float* out = (float*)d_out;

    u16* Sn = (u16*)d_ws;                        // 2080*512 bf16 (padded)
    u16* Qn = Sn + (size_t)MPAD * D;             // 16000*512 bf16
    float* cum = (float*)(Qn + (size_t)NROWS * D);  // 25*200 f32 (fully overwritten)

    normalize_kernel<<<4501, 256, 0, stream>>>(sg, sl, qg, ql, Sn, Qn);
    dim3 g2(100, 13);
    gemm_kernel<<<g2, 256, 0, stream>>>(Sn, Qn, cum);
    logits_kernel<<<(NQ * WAY + 255) / 256, 256, 0, stream>>>(cum, labels, out);
}

// Round 4
// 108.492 us; speedup vs baseline: 1.6118x; 1.4179x over previous
//
#include <hip/hip_runtime.h>

#define NS 25
#define NQ 200
#define FG 16
#define FL 64
#define FTOT 80
#define D 512
#define WAY 5
#define MROWS 2000    // 25*80 support rows
#define MPAD 2080     // padded to 13 tiles of 160
#define NROWS 16000   // 200*80 query rows

typedef unsigned char u8;
typedef __attribute__((ext_vector_type(4))) float floatx4;
typedef __attribute__((ext_vector_type(4))) int intx4;

__device__ inline void gload_lds16(const void* g, void* l) {
    __builtin_amdgcn_global_load_lds(
        (const __attribute__((address_space(1))) unsigned int*)g,
        (__attribute__((address_space(3))) unsigned int*)l, 16, 0, 0);
}

// One wave per 512-elem row: L2-normalize, cast fp8 e4m3 (OCP), write concat
// layout. Block 4500: zero Sn pad rows + zero out[] + per-class 1/count.
__global__ void normalize_kernel(const float* __restrict__ sg, const float* __restrict__ sl,
                                 const float* __restrict__ qg, const float* __restrict__ ql,
                                 u8* __restrict__ Sn, u8* __restrict__ Qn,
                                 const int* __restrict__ labels,
                                 float* __restrict__ out, float* __restrict__ rcnt) {
    if (blockIdx.x == 4500) {
        intx4 z = {0, 0, 0, 0};
        intx4* pad = (intx4*)(Sn + (size_t)MROWS * D);   // 80 rows * 512 B = 2560 intx4
        for (int i = threadIdx.x; i < (MPAD - MROWS) * D / 16; i += 256) pad[i] = z;
        for (int i = threadIdx.x; i < NQ * WAY; i += 256) out[i] = 0.f;
        if (threadIdx.x == 0) {
            int counts[WAY] = {0, 0, 0, 0, 0};
            for (int s = 0; s < NS; ++s) counts[labels[s]]++;
            for (int c = 0; c < WAY; ++c) rcnt[c] = 1.0f / (float)(counts[c] ? counts[c] : 1);
        }
        return;
    }
    int wave = (blockIdx.x * blockDim.x + threadIdx.x) >> 6;
    int lane = threadIdx.x & 63;
    const int totalRows = MROWS + NROWS;   // 18000
    if (wave >= totalRows) return;

    const float* src;
    u8* dst;
    if (wave < MROWS) {
        int s = wave / FTOT, f = wave % FTOT;
        src = (f < FG) ? sg + (size_t)(s * FG + f) * D
                       : sl + (size_t)(s * FL + (f - FG)) * D;
        dst = Sn + (size_t)wave * D;
    } else {
        int r = wave - MROWS;
        int q = r / FTOT, f = r % FTOT;
        src = (f < FG) ? qg + (size_t)(q * FG + f) * D
                       : ql + (size_t)(q * FL + (f - FG)) * D;
        dst = Qn + (size_t)r * D;
    }

    // lane holds 8 contiguous elements [8*lane .. 8*lane+8)
    float4 v0 = ((const float4*)src)[2 * lane];
    float4 v1 = ((const float4*)src)[2 * lane + 1];
    float ss = v0.x*v0.x + v0.y*v0.y + v0.z*v0.z + v0.w*v0.w
             + v1.x*v1.x + v1.y*v1.y + v1.z*v1.z + v1.w*v1.w;
    #pragma unroll
    for (int off = 32; off > 0; off >>= 1) ss += __shfl_xor(ss, off, 64);
    float scale = 1.0f / fmaxf(sqrtf(ss), 1e-12f);

    int w0 = __builtin_amdgcn_cvt_pk_fp8_f32(v0.x * scale, v0.y * scale, 0, false);
    w0     = __builtin_amdgcn_cvt_pk_fp8_f32(v0.z * scale, v0.w * scale, w0, true);
    int w1 = __builtin_amdgcn_cvt_pk_fp8_f32(v1.x * scale, v1.y * scale, 0, false);
    w1     = __builtin_amdgcn_cvt_pk_fp8_f32(v1.z * scale, v1.w * scale, w1, true);
    ((int2*)dst)[lane] = make_int2(w0, w1);
}

// 160x160-tile fp8 NT GEMM aligned to 80-row groups; BK=128, XOR-swizzled LDS.
// 4 waves 2x2, each owns one 80x80 (s,q) block = 5x5 MFMA 16x16x32 fp8 tiles.
// Epilogue: sum (1-sim)^2 -> fused class-mean logits via one atomic per wave.
__global__ __launch_bounds__(256, 3) void gemm_kernel(const u8* __restrict__ Sn,
                                                      const u8* __restrict__ Qn,
                                                      const int* __restrict__ labels,
                                                      const float* __restrict__ rcnt,
                                                      float* __restrict__ out) {
    __shared__ u8 As[160][128];   // fp8, BK=128; 16B chunk c holds global chunk c^((r>>1)&7)
    __shared__ u8 Bs[160][128];

    const int bx = blockIdx.x;          // 0..99  (query groups, 2 per block)
    const int by = blockIdx.y;          // 0..12  (support groups, 2 per block)
    const int tid = threadIdx.x;
    const int lane = tid & 63;
    const int w = tid >> 6;
    const int lm = lane & 15;
    const int lq = lane >> 4;
    const int wr = w >> 1;              // which 80-row half
    const int wc = w & 1;               // which 80-col half

    floatx4 acc[5][5];
    #pragma unroll
    for (int i = 0; i < 5; ++i)
        #pragma unroll
        for (int j = 0; j < 5; ++j) acc[i][j] = (floatx4){0.f, 0.f, 0.f, 0.f};

    const u8* Sbase = Sn + (size_t)by * 160 * D;
    const u8* Qbase = Qn + (size_t)bx * 160 * D;

    // staging: waves 0,1 -> A; waves 2,3 -> B. 20 slabs of 8 rows (1 KB each).
    const u8* gsrc = (w < 2) ? Sbase : Qbase;
    u8* ldst = (w < 2) ? (u8*)As : (u8*)Bs;
    const int sl0 = (w & 1) * 10;
    const int grow = lane >> 3;         // row within 8-row slab
    const int gc = lane & 7;            // 16B slot-chunk within 128B row

    // fragment read indices: lane reads 8B at k-chunk c' = ks*2+(lq>>1),
    // stored in slot chunk c'^((r>>1)&7), byte offset (lq&1)*8
    #pragma unroll 1
    for (int kc = 0; kc < 4; ++kc) {
        const int k0 = kc * 128;
        __syncthreads();                // prev chunk's readers done
        #pragma unroll
        for (int t = 0; t < 10; ++t) {
            const int sl = sl0 + t;
            const int r = sl * 8 + grow;
            const int cp = gc ^ ((r >> 1) & 7);
            gload_lds16(gsrc + (size_t)r * D + k0 + cp * 16, ldst + sl * 1024);
        }
        __syncthreads();                // drains vmcnt (global_load_lds) too
        #pragma unroll
        for (int ks = 0; ks < 4; ++ks) {
            long long a[5], b[5];
            #pragma unroll
            for (int i = 0; i < 5; ++i) {
                const int r = wr * 80 + i * 16 + lm;
                const int c = (ks * 2 + (lq >> 1)) ^ ((r >> 1) & 7);
                a[i] = *(const long long*)(&As[r][c * 16 + (lq & 1) * 8]);
            }
            #pragma unroll
            for (int j = 0; j < 5; ++j) {
                const int r = wc * 80 + j * 16 + lm;
                const int c = (ks * 2 + (lq >> 1)) ^ ((r >> 1) & 7);
                b[j] = *(const long long*)(&Bs[r][c * 16 + (lq & 1) * 8]);
            }
            #pragma unroll
            for (int i = 0; i < 5; ++i)
                #pragma unroll
                for (int j = 0; j < 5; ++j)
                    acc[i][j] = __builtin_amdgcn_mfma_f32_16x16x32_fp8_fp8(a[i], b[j], acc[i][j], 0, 0, 0);
        }
    }

    // Epilogue: sum (1-sim)^2 over the wave's 80x80 block, fuse class-mean.
    float local = 0.f;
    #pragma unroll
    for (int i = 0; i < 5; ++i)
        #pragma unroll
        for (int j = 0; j < 5; ++j)
            #pragma unroll
            for (int r = 0; r < 4; ++r) {
                const float d = 1.0f - acc[i][j][r];
                local = fmaf(d, d, local);
            }
    #pragma unroll
    for (int off = 32; off > 0; off >>= 1) local += __shfl_down(local, off, 64);

    const int sIdx = by * 2 + wr;       // 25 = pad group, dropped
    const int qIdx = bx * 2 + wc;
    if (lane == 0 && sIdx < NS) {
        const int c = labels[sIdx];
        atomicAdd(&out[qIdx * WAY + c], -2.0f * local * rcnt[c]);
    }
}

extern "C" void kernel_launch(void* const* d_in, const int* in_sizes, int n_in,
                              void* d_out, int out_size, void* d_ws, size_t ws_size,
                              hipStream_t stream) {
    const float* sg = (const float*)d_in[0];
    const float* sl = (const float*)d_in[1];
    const int* labels = (const int*)d_in[2];
    const float* qg = (const float*)d_in[3];
    const float* ql = (const float*)d_in[4];
    float* out = (float*)d_out;

    u8* Sn = (u8*)d_ws;                          // 2080*512 fp8 (padded)
    u8* Qn = Sn + (size_t)MPAD * D;              // 16000*512 fp8
    float* rcnt = (float*)(Qn + (size_t)NROWS * D);

    normalize_kernel<<<4501, 256, 0, stream>>>(sg, sl, qg, ql, Sn, Qn, labels, out, rcnt);
    dim3 g2(100, 13);
    gemm_kernel<<<g2, 256, 0, stream>>>(Sn, Qn, labels, rcnt, out);
}